// Round 1
// baseline (2090.816 us; speedup 1.0000x reference)
//
#include <hip/hip_runtime.h>
#include <cstdint>
#include <cstddef>

typedef short s16x8 __attribute__((ext_vector_type(8)));
typedef float f32x4 __attribute__((ext_vector_type(4)));
typedef unsigned long long u64;

__device__ __forceinline__ f32x4 mfma16(s16x8 a, s16x8 b, f32x4 c) {
  return __builtin_amdgcn_mfma_f32_16x16x32_bf16(a, b, c, 0, 0, 0);
}

__device__ __forceinline__ unsigned short f2bf(float f) {
  unsigned u = __float_as_uint(f);
  u = (u + 0x7FFFu + ((u >> 16) & 1u)) >> 16;
  return (unsigned short)u;
}

// LLC-coherent ops (bypass L1/L2, hit the coherence point directly).
__device__ __forceinline__ u64 ld_llc64(const u64* q) {
  return __hip_atomic_load(q, __ATOMIC_RELAXED, __HIP_MEMORY_SCOPE_AGENT);
}
__device__ __forceinline__ float4 load16f_llc(const float* p) {
  union { u64 u[2]; float4 v; } r;
  const u64* q = (const u64*)p;
  r.u[0] = __hip_atomic_load(q,     __ATOMIC_RELAXED, __HIP_MEMORY_SCOPE_AGENT);
  r.u[1] = __hip_atomic_load(q + 1, __ATOMIC_RELAXED, __HIP_MEMORY_SCOPE_AGENT);
  return r.v;
}
__device__ __forceinline__ void store16f_llc(float* p, float4 v) {
  union { float4 v; u64 u[2]; } r; r.v = v;
  u64* q = (u64*)p;
  __hip_atomic_store(q,     r.u[0], __ATOMIC_RELAXED, __HIP_MEMORY_SCOPE_AGENT);
  __hip_atomic_store(q + 1, r.u[1], __ATOMIC_RELAXED, __HIP_MEMORY_SCOPE_AGENT);
}
__device__ __forceinline__ void spin_tag(const int* t, int target) {
  while (__hip_atomic_load(t, __ATOMIC_RELAXED, __HIP_MEMORY_SCOPE_AGENT) < target)
    __builtin_amdgcn_s_sleep(1);
}

// Stamped-fragment wait+pack: 8 words of (stamp<<16 | bf16) -> s16x8 of the
// bf16 lo-halves. Spins (per-lane, exec-masked) until ALL 8 stamps match.
// Equality-poll is safe: the anti-trample guards guarantee a slot's stamp
// never advances past `want` before every reader consumed it.
__device__ __forceinline__ s16x8 frag_finish(const u64* q, u64 r0, u64 r1,
                                             u64 r2, u64 r3, u64 want) {
  const u64 m = 0xFFFF0000FFFF0000ull;
  while (((r0 & m) != want) | ((r1 & m) != want) |
         ((r2 & m) != want) | ((r3 & m) != want)) {
    r0 = ld_llc64(q);     r1 = ld_llc64(q + 1);
    r2 = ld_llc64(q + 2); r3 = ld_llc64(q + 3);
  }
  union { unsigned u[4]; s16x8 v; } o;
  o.u[0] = __builtin_amdgcn_perm((unsigned)(r0 >> 32), (unsigned)r0, 0x05040100u);
  o.u[1] = __builtin_amdgcn_perm((unsigned)(r1 >> 32), (unsigned)r1, 0x05040100u);
  o.u[2] = __builtin_amdgcn_perm((unsigned)(r2 >> 32), (unsigned)r2, 0x05040100u);
  o.u[3] = __builtin_amdgcn_perm((unsigned)(r3 >> 32), (unsigned)r3, 0x05040100u);
  return o.v;
}

// ---------------- fp32 -> bf16 conversion ----------------
__global__ void f2bf_kernel(const float* __restrict__ src,
                            unsigned short* __restrict__ dst, int n) {
  int i = (blockIdx.x * blockDim.x + threadIdx.x) * 4;
  if (i >= n) return;
  float4 v = *(const float4*)(src + i);
  ushort4 o;
  o.x = f2bf(v.x); o.y = f2bf(v.y); o.z = f2bf(v.z); o.w = f2bf(v.w);
  *(ushort4*)(dst + i) = o;
}

// ---------------- GEMM: C[M,N] = A[M,K] * W[N,K]^T + bias ----------------
__global__ __launch_bounds__(256) void gemm_bias(
    const unsigned short* __restrict__ A,
    const unsigned short* __restrict__ W,
    const float* __restrict__ bias,
    float* __restrict__ C,
    int M, int N, int K)
{
  __shared__ unsigned short As[128 * 40];
  __shared__ unsigned short Bs[128 * 40];
  const int bm = blockIdx.x, bn = blockIdx.y;
  const int tid = threadIdx.x;
  const int lane = tid & 63, wave = tid >> 6;
  const int wm = wave & 1, wn = wave >> 1;
  const int lr = lane & 15, quad = lane >> 4;
  f32x4 acc[4][4] = {};
  const size_t abase = (size_t)bm * 128 * K;
  const size_t bbase = (size_t)bn * 128 * K;
  for (int k0 = 0; k0 < K; k0 += 32) {
#pragma unroll
    for (int u0 = 0; u0 < 2; u0++) {
      int u = tid + u0 * 256;
      int row = u >> 2, seg = u & 3;
      *(uint4*)(As + row * 40 + seg * 8) =
          *(const uint4*)(A + abase + (size_t)row * K + k0 + seg * 8);
      *(uint4*)(Bs + row * 40 + seg * 8) =
          *(const uint4*)(W + bbase + (size_t)row * K + k0 + seg * 8);
    }
    __syncthreads();
    s16x8 af[4], bf[4];
#pragma unroll
    for (int i = 0; i < 4; i++)
      af[i] = *(const s16x8*)(As + (wm * 64 + i * 16 + lr) * 40 + quad * 8);
#pragma unroll
    for (int j = 0; j < 4; j++)
      bf[j] = *(const s16x8*)(Bs + (wn * 64 + j * 16 + lr) * 40 + quad * 8);
#pragma unroll
    for (int i = 0; i < 4; i++)
#pragma unroll
      for (int j = 0; j < 4; j++)
        acc[i][j] = mfma16(af[i], bf[j], acc[i][j]);
    __syncthreads();
  }
#pragma unroll
  for (int i = 0; i < 4; i++)
#pragma unroll
    for (int j = 0; j < 4; j++) {
      int col = bn * 128 + wn * 64 + j * 16 + lr;
      float bv = bias ? bias[col] : 0.0f;
#pragma unroll
      for (int r = 0; r < 4; r++) {
        int row = bm * 128 + wm * 64 + i * 16 + quad * 4 + r;
        C[(size_t)row * N + col] = acc[i][j][r] + bv;
      }
    }
}

// ---------------- dataflow 3-stage pipelined LSTM ----------------
// R7: data-is-the-flag. h1/h2 exchanged as 32-bit words (stamp<<16 | bf16),
// stamp = step+1, zero-init == step -1 (h(-1)=0). Consumers poll the exact
// fragment words they feed to MFMA -> forward path is ONE LLC hop (producer
// fire-and-forget store -> consumer poll). The old forward tags become
// lagging read-completion guards placed AFTER the load+MFMA+reduce work
// (pre-satisfied in steady state). vmcnt(0)-before-tag kept only for cls1
// (its tag certifies P stores visible); cls0/cls2 tags certify reads only.
//   cls0 L1 : h1(s) = gate(ih(s) + Whh0 h1(s-1))   reads h1 stamps s
//   cls1 L2b: P(s)  = Wih1 h1(s) + b1  -> 4-ring   reads h1 stamps s+1; tag2b
//   cls2 L2a: h2(s) = gate(P(s) + Whh1 h2(s-1))    reads h2 stamps s; writes out
// Anti-trample (all lagging): cls0 store h1(s) needs tagL1>=s (peers read
// h1(s-2)) and tagL2b>=s-1 (cls1 read h1(s-2)). cls2 store h2(s) needs
// tagL2a>=s. cls1 P-ring reuse needs partner tagL2a>=s-3. Stamp-equality
// polling is deadlock-free because these guards order every slot overwrite
// after all consumptions of the previous stamp.
#define TSTRIDE 32          // ints per tag (128B line)
#define HSLOT  32768        // u32 words per h slot: 64 blk * 32 batch * 16 dim
#define PSLOT  (64 * 2048)  // floats per P slot: 64 blk * 32 batch * 64 col

__global__ __launch_bounds__(512, 2) void lstm_pipe(
    const float* __restrict__ ih,             // [(b*T+t)*4096 + g*1024 + d]
    const unsigned short* __restrict__ Whh0,  // [4096,1024] bf16
    const unsigned short* __restrict__ Wih1,  // [4096,1024] bf16
    const unsigned short* __restrict__ Whh1,  // [4096,1024] bf16
    const float* __restrict__ b1,             // [4096] fp32
    unsigned* __restrict__ h1x,               // [2][64][32][16] u32 (zeroed)
    unsigned* __restrict__ h2x,               // [2][64][32][16] u32 (zeroed)
    float* __restrict__ Pring,                // [4][64][32][64] fp32
    int* __restrict__ tags,                   // [3][64][TSTRIDE] (zeroed)
    float* __restrict__ out)                  // [32][256][1024] fp32
{
  const int T = 256, H = 1024;
  const int cls = blockIdx.x >> 6;
  const int blk = blockIdx.x & 63;
  const int tid = threadIdx.x;
  const int lane = tid & 63, wv = tid >> 6;
  const int lr = lane & 15, quad = lane >> 4;

  __shared__ float red[8][32][68];
  __shared__ float pre[32][68];

  const unsigned short* W = (cls == 0) ? Whh0 : (cls == 1) ? Wih1 : Whh1;
  s16x8 bfrag[4][4];
#pragma unroll
  for (int g = 0; g < 4; g++) {
    const unsigned short* wp =
        W + (size_t)(g * 1024 + blk * 16 + lr) * 1024 + wv * 128 + quad * 8;
#pragma unroll
    for (int kb = 0; kb < 4; kb++) bfrag[g][kb] = *(const s16x8*)(wp + kb * 32);
  }

  int* tagL1  = tags;
  int* tagL2b = tags + 64 * TSTRIDE;
  int* tagL2a = tags + 128 * TSTRIDE;
  int* mytag  = tags + (cls * 64 + blk) * TSTRIDE;

  const int batch = tid >> 4, jj = tid & 15;
  float cst = 0.0f;

  const int o = tid * 4;
  const int b2 = o >> 6, col0 = o & 63;
  const int gg_ = col0 >> 4, j0 = col0 & 15;
  const float* ihp0 = ih + (size_t)b2 * T * 4096 + gg_ * 1024 + blk * 16 + j0;

  float4 iv = {0.f, 0.f, 0.f, 0.f};
  if (cls == 0)      iv = *(const float4*)(ihp0);
  else if (cls == 1) iv = *(const float4*)(b1 + gg_ * 1024 + blk * 16 + j0);

  for (int s = 0; s < T; s++) {
    // ---- start polls: only the non-stamped (fp32 P-ring) dependencies ----
    if (cls == 1) {
      if (lane == 0) spin_tag(tagL2a + blk * TSTRIDE, s - 3);  // P-ring reuse
    } else if (cls == 2) {
      if (lane == 0) spin_tag(tagL2b + blk * TSTRIDE, s + 1);  // partner P(s)
    }
    asm volatile("" ::: "memory");

    // source: cls0 h1(s-1); cls1 h1(s); cls2 h2(s-1). slot = step & 1.
    const unsigned* hsrc =
        (cls == 0) ? h1x + ((s + 1) & 1) * HSLOT
      : (cls == 1) ? h1x + (s & 1) * HSLOT
                   : h2x + ((s + 1) & 1) * HSLOT;
    const unsigned stamp = (cls == 1) ? (unsigned)(s + 1) : (unsigned)s;
    const u64 want = ((u64)stamp << 16) | ((u64)stamp << 48);

    // issue ALL fragment loads up-front (one LLC latency for the whole step)
    u64 rA[4][4], rB[4][4];
#pragma unroll
    for (int kb = 0; kb < 4; kb++) {
      const int d = wv * 128 + kb * 32 + quad * 8;       // global k-dim
      const unsigned* pp = hsrc + (d >> 4) * 512 + (d & 15);
      const u64* q0 = (const u64*)(pp + lr * 16);
      const u64* q1 = (const u64*)(pp + (16 + lr) * 16);
#pragma unroll
      for (int w = 0; w < 4; w++) {
        rA[kb][w] = ld_llc64(q0 + w);
        rB[kb][w] = ld_llc64(q1 + w);
      }
    }

    f32x4 acc0[4] = {}, acc1[4] = {};
#pragma unroll
    for (int kb = 0; kb < 4; kb++) {
      const int d = wv * 128 + kb * 32 + quad * 8;
      const unsigned* pp = hsrc + (d >> 4) * 512 + (d & 15);
      const u64* q0 = (const u64*)(pp + lr * 16);
      const u64* q1 = (const u64*)(pp + (16 + lr) * 16);
      s16x8 a0 = frag_finish(q0, rA[kb][0], rA[kb][1], rA[kb][2], rA[kb][3], want);
      s16x8 a1 = frag_finish(q1, rB[kb][0], rB[kb][1], rB[kb][2], rB[kb][3], want);
#pragma unroll
      for (int g = 0; g < 4; g++) {
        acc0[g] = mfma16(a0, bfrag[g][kb], acc0[g]);
        acc1[g] = mfma16(a1, bfrag[g][kb], acc1[g]);
      }
    }
#pragma unroll
    for (int g = 0; g < 4; g++)
#pragma unroll
      for (int r = 0; r < 4; r++) {
        red[wv][quad * 4 + r][g * 16 + lr] = acc0[g][r];
        red[wv][16 + quad * 4 + r][g * 16 + lr] = acc1[g][r];
      }
    __syncthreads();  // A

    // ---- reduce 8 partials + iv (cls2: iv = partner's P(s) from ring) ----
    float4 sm;
    if (cls == 2)
      sm = load16f_llc(Pring + (size_t)(s & 3) * PSLOT + blk * 2048 + b2 * 64 + col0);
    else
      sm = iv;
#pragma unroll
    for (int p = 0; p < 8; p++) {
      float4 r = *(const float4*)&red[p][b2][col0];
      sm.x += r.x; sm.y += r.y; sm.z += r.z; sm.w += r.w;
    }

    // ---- lagging anti-trample guards (pre-satisfied in steady state) ----
    if (cls == 0) {
      if (tid < 64)       spin_tag(tagL1 + tid * TSTRIDE, s);          // peers read h1(s-2)
      else if (tid < 128) spin_tag(tagL2b + (tid - 64) * TSTRIDE, s - 1); // cls1 read h1(s-2)
      if (s + 1 < T) iv = *(const float4*)(ihp0 + (size_t)(s + 1) * 4096);
    } else if (cls == 2) {
      if (tid < 64) spin_tag(tagL2a + tid * TSTRIDE, s);               // peers read h2(s-2)
    }

    if (cls == 1) {
      // P(s) = pre-activations, straight to the ring (no gates, no syncB)
      store16f_llc(Pring + (size_t)(s & 3) * PSLOT + blk * 2048 + b2 * 64 + col0, sm);
    } else {
      *(float4*)&pre[b2][col0] = sm;
      __syncthreads();  // B (also orders guards before the stamped store)
      float pi = pre[batch][jj];
      float pf = pre[batch][16 + jj];
      float pg = pre[batch][32 + jj];
      float po = pre[batch][48 + jj];
      float ig = 1.0f / (1.0f + __expf(-pi));
      float fg = 1.0f / (1.0f + __expf(-pf));
      float g  = 1.0f - 2.0f / (__expf(2.0f * pg) + 1.0f);  // tanh, safe
      float og = 1.0f / (1.0f + __expf(-po));
      cst = fg * cst + ig * g;
      float hv = og * (1.0f - 2.0f / (__expf(2.0f * cst) + 1.0f));
      // stamped publish: the store IS the flag (fire-and-forget, 1 LLC hop)
      unsigned word = ((unsigned)(s + 1) << 16) | (unsigned)f2bf(hv);
      unsigned* dst = (cls == 0 ? h1x : h2x) + (s & 1) * HSLOT;
      __hip_atomic_store(dst + blk * 512 + batch * 16 + jj, word,
                         __ATOMIC_RELAXED, __HIP_MEMORY_SCOPE_AGENT);
      if (cls == 2)
        out[((size_t)(batch * T + s)) * H + blk * 16 + jj] = hv;
    }
    // cls1's tag certifies P stores visible -> drain. cls0/cls2 tags certify
    // reads only (consumed by MFMA before syncA) -> no drain needed.
    if (cls == 1) asm volatile("s_waitcnt vmcnt(0)" ::: "memory");
    __syncthreads();  // C
    if (tid == 0)
      __hip_atomic_store(mytag, s + 1, __ATOMIC_RELAXED, __HIP_MEMORY_SCOPE_AGENT);
  }
}

// ---------------- launcher ----------------
extern "C" void kernel_launch(void* const* d_in, const int* in_sizes, int n_in,
                              void* d_out, int out_size, void* d_ws, size_t ws_size,
                              hipStream_t stream) {
  const float* x    = (const float*)d_in[0];
  const float* Wih0 = (const float*)d_in[1];
  const float* Whh0 = (const float*)d_in[2];
  const float* b0   = (const float*)d_in[3];
  const float* Wih1 = (const float*)d_in[4];
  const float* Whh1 = (const float*)d_in[5];
  const float* b1   = (const float*)d_in[6];
  float* out = (float*)d_out;

  const size_t NW = 4096ull * 1024;  // weight elems
  const size_t NX = 8192ull * 1024;  // x elems (B*T x H)

  char* ws = (char*)d_ws;
  size_t off = 0;
  auto alloc = [&](size_t bytes) {
    char* p = ws + off;
    off += (bytes + 255) & ~(size_t)255;
    return p;
  };
  unsigned short* wih0b = (unsigned short*)alloc(NW * 2);
  unsigned short* whh0b = (unsigned short*)alloc(NW * 2);
  unsigned short* wih1b = (unsigned short*)alloc(NW * 2);
  unsigned short* whh1b = (unsigned short*)alloc(NW * 2);
  unsigned short* xb    = (unsigned short*)alloc(NX * 2);
  float* ihbuf          = (float*)alloc(8192ull * 4096 * 4);
  unsigned* h1x         = (unsigned*)alloc(2ull * HSLOT * 4);
  unsigned* h2x         = (unsigned*)alloc(2ull * HSLOT * 4);
  float* Pring          = (float*)alloc(4ull * PSLOT * 4);
  int* tags             = (int*)alloc(3ull * 64 * TSTRIDE * 4);

  hipMemsetAsync(tags, 0, 3ull * 64 * TSTRIDE * 4, stream);
  hipMemsetAsync(h1x, 0, 2ull * HSLOT * 4, stream);
  hipMemsetAsync(h2x, 0, 2ull * HSLOT * 4, stream);

  f2bf_kernel<<<NW / 1024, 256, 0, stream>>>(Wih0, wih0b, (int)NW);
  f2bf_kernel<<<NW / 1024, 256, 0, stream>>>(Whh0, whh0b, (int)NW);
  f2bf_kernel<<<NW / 1024, 256, 0, stream>>>(Wih1, wih1b, (int)NW);
  f2bf_kernel<<<NW / 1024, 256, 0, stream>>>(Whh1, whh1b, (int)NW);
  f2bf_kernel<<<NX / 1024, 256, 0, stream>>>(x, xb, (int)NX);

  // layer-1 input projection (one big GEMM), then the dataflow pipeline
  gemm_bias<<<dim3(64, 32), 256, 0, stream>>>(xb, wih0b, b0, ihbuf, 8192, 4096, 1024);
  lstm_pipe<<<192, 512, 0, stream>>>(ihbuf, whh0b, wih1b, whh1b, b1,
                                     h1x, h2x, Pring, tags, out);
}

// Round 3
// 1602.378 us; speedup vs baseline: 1.3048x; 1.3048x over previous
//
#include <hip/hip_runtime.h>
#include <cstdint>
#include <cstddef>

typedef short s16x8 __attribute__((ext_vector_type(8)));
typedef float f32x4 __attribute__((ext_vector_type(4)));
typedef unsigned long long u64;

__device__ __forceinline__ f32x4 mfma16(s16x8 a, s16x8 b, f32x4 c) {
  return __builtin_amdgcn_mfma_f32_16x16x32_bf16(a, b, c, 0, 0, 0);
}

__device__ __forceinline__ unsigned short f2bf(float f) {
  unsigned u = __float_as_uint(f);
  u = (u + 0x7FFFu + ((u >> 16) & 1u)) >> 16;
  return (unsigned short)u;
}

// LLC-coherent ops (bypass L1/L2, hit the coherence point directly).
__device__ __forceinline__ u64 ld_llc64(const u64* q) {
  return __hip_atomic_load(q, __ATOMIC_RELAXED, __HIP_MEMORY_SCOPE_AGENT);
}
__device__ __forceinline__ float4 load16f_llc(const float* p) {
  union { u64 u[2]; float4 v; } r;
  const u64* q = (const u64*)p;
  r.u[0] = __hip_atomic_load(q,     __ATOMIC_RELAXED, __HIP_MEMORY_SCOPE_AGENT);
  r.u[1] = __hip_atomic_load(q + 1, __ATOMIC_RELAXED, __HIP_MEMORY_SCOPE_AGENT);
  return r.v;
}
__device__ __forceinline__ void store16f_llc(float* p, float4 v) {
  union { float4 v; u64 u[2]; } r; r.v = v;
  u64* q = (u64*)p;
  __hip_atomic_store(q,     r.u[0], __ATOMIC_RELAXED, __HIP_MEMORY_SCOPE_AGENT);
  __hip_atomic_store(q + 1, r.u[1], __ATOMIC_RELAXED, __HIP_MEMORY_SCOPE_AGENT);
}

// Pipelined spin: keep 3 tag loads in flight so the observe-slip after the
// producer's add lands is ~max(RT/3, sleep) instead of a full RT per retry.
// s_sleep(1) in the steady loop keeps poll pressure off the LLC.
__device__ __forceinline__ void spin_tag(const int* t, int target) {
  if (target <= 0) return;
  int a = __hip_atomic_load(t, __ATOMIC_RELAXED, __HIP_MEMORY_SCOPE_AGENT);
  if (a >= target) return;
  int b = __hip_atomic_load(t, __ATOMIC_RELAXED, __HIP_MEMORY_SCOPE_AGENT);
  int c = __hip_atomic_load(t, __ATOMIC_RELAXED, __HIP_MEMORY_SCOPE_AGENT);
  while (a < target) {
    a = b; b = c;
    __builtin_amdgcn_s_sleep(1);
    c = __hip_atomic_load(t, __ATOMIC_RELAXED, __HIP_MEMORY_SCOPE_AGENT);
  }
}

// ---------------- fp32 -> bf16 conversion ----------------
__global__ void f2bf_kernel(const float* __restrict__ src,
                            unsigned short* __restrict__ dst, int n) {
  int i = (blockIdx.x * blockDim.x + threadIdx.x) * 4;
  if (i >= n) return;
  float4 v = *(const float4*)(src + i);
  ushort4 o;
  o.x = f2bf(v.x); o.y = f2bf(v.y); o.z = f2bf(v.z); o.w = f2bf(v.w);
  *(ushort4*)(dst + i) = o;
}

// ---------------- GEMM: C[M,N] = A[M,K] * W[N,K]^T + bias ----------------
__global__ __launch_bounds__(256) void gemm_bias(
    const unsigned short* __restrict__ A,
    const unsigned short* __restrict__ W,
    const float* __restrict__ bias,
    float* __restrict__ C,
    int M, int N, int K)
{
  __shared__ unsigned short As[128 * 40];
  __shared__ unsigned short Bs[128 * 40];
  const int bm = blockIdx.x, bn = blockIdx.y;
  const int tid = threadIdx.x;
  const int lane = tid & 63, wave = tid >> 6;
  const int wm = wave & 1, wn = wave >> 1;
  const int lr = lane & 15, quad = lane >> 4;
  f32x4 acc[4][4] = {};
  const size_t abase = (size_t)bm * 128 * K;
  const size_t bbase = (size_t)bn * 128 * K;
  for (int k0 = 0; k0 < K; k0 += 32) {
#pragma unroll
    for (int u0 = 0; u0 < 2; u0++) {
      int u = tid + u0 * 256;
      int row = u >> 2, seg = u & 3;
      *(uint4*)(As + row * 40 + seg * 8) =
          *(const uint4*)(A + abase + (size_t)row * K + k0 + seg * 8);
      *(uint4*)(Bs + row * 40 + seg * 8) =
          *(const uint4*)(W + bbase + (size_t)row * K + k0 + seg * 8);
    }
    __syncthreads();
    s16x8 af[4], bf[4];
#pragma unroll
    for (int i = 0; i < 4; i++)
      af[i] = *(const s16x8*)(As + (wm * 64 + i * 16 + lr) * 40 + quad * 8);
#pragma unroll
    for (int j = 0; j < 4; j++)
      bf[j] = *(const s16x8*)(Bs + (wn * 64 + j * 16 + lr) * 40 + quad * 8);
#pragma unroll
    for (int i = 0; i < 4; i++)
#pragma unroll
      for (int j = 0; j < 4; j++)
        acc[i][j] = mfma16(af[i], bf[j], acc[i][j]);
    __syncthreads();
  }
#pragma unroll
  for (int i = 0; i < 4; i++)
#pragma unroll
    for (int j = 0; j < 4; j++) {
      int col = bn * 128 + wn * 64 + j * 16 + lr;
      float bv = bias ? bias[col] : 0.0f;
#pragma unroll
      for (int r = 0; r < 4; r++) {
        int row = bm * 128 + wm * 64 + i * 16 + quad * 4 + r;
        C[(size_t)row * N + col] = acc[i][j][r] + bv;
      }
    }
}

// ---------------- dataflow 3-stage pipelined LSTM ----------------
// R9 = R8 with two fixes (R8 bench died at container level, no profile):
//   FIX1: cls1 had an LDS WAR race on red[] after syncC removal (no barrier
//         between step-s red reads and step-s+1 red writes). cls1 now runs a
//         barrier in its tail (after the P store, before drain/publish).
//         cls0/cls2 were already safe via syncB.
//   FIX2: restore s_sleep(1) in the spin retry loop (R8 polled sleepless).
// R8 deltas kept:
//   1. Pipelined depth-3 tag polls -> observe slip ~max(RT/3, 64cy).
//   2. Per-wave tag adds: tag = 8 * completed-steps. Each wave drains its own
//      stores (vmcnt(0)) then atomicAdd(mytag,1). No block-wide rendezvous in
//      the tail; wave wv polls exactly the 8 producer blocks it consumes.
//      syncA bounds intra-block wave skew to 1 step, so tag >= 8(s+1) implies
//      every wave of that block completed step s.
//   3. h1x/h2x rings deepened 2 -> 4 slots: cls0's h1-slot guard relaxes to
//      tagL2b >= 8(s-3) (pre-satisfied in steady state), decoupling cls0's
//      period from cls1's full chain latency.
//   4. cls2: P-ring load issued right after polls (hides under MFMA);
//      out[] store moved after the tag add (not part of the drain).
// Classes (64 blocks each, 16 output dims per block, weights in VGPRs):
//   cls0 L1 : h1(s) = gate(ih(s) + Whh0 h1(s-1))   tagL1
//   cls1 L2b: P(s)  = Wih1 h1(s) + b1  -> 4-ring   tagL2b (point-to-point)
//   cls2 L2a: h2(s) = gate(P(s) + Whh1 h2(s-1))    tagL2a; writes out
// Anti-trample: all slot overwrites are ordered (via wave-order or barrier
// transitivity) after every consumption of the previous occupant:
//   cls0 h1(s): top polls (collectively all 64 peers >= 8s, before syncB <
//   stores) + tid<64 guard tagL2b >= 8(s-3). cls1 P(s): lane-0 guard partner
//   tagL2a >= 8(s-3). cls2 h2(s): top polls tagL2a >= 8s (collective).
#define TSTRIDE 32          // ints per tag (128B line)
#define HSLOT  32768        // shorts per h slot: 64 blk * 32 batch * 16 dim
#define PSLOT  (64 * 2048)  // floats per P slot: 64 blk * 32 batch * 64 col

__global__ __launch_bounds__(512, 2) void lstm_pipe(
    const float* __restrict__ ih,             // [(b*T+t)*4096 + g*1024 + d]
    const unsigned short* __restrict__ Whh0,  // [4096,1024] bf16
    const unsigned short* __restrict__ Wih1,  // [4096,1024] bf16
    const unsigned short* __restrict__ Whh1,  // [4096,1024] bf16
    const float* __restrict__ b1,             // [4096] fp32
    unsigned short* __restrict__ h1x,         // [4][64][32][16] bf16 (zeroed)
    unsigned short* __restrict__ h2x,         // [4][64][32][16] bf16 (zeroed)
    float* __restrict__ Pring,                // [4][64][32][64] fp32
    int* __restrict__ tags,                   // [3][64][TSTRIDE] (zeroed)
    float* __restrict__ out)                  // [32][256][1024] fp32
{
  const int T = 256, H = 1024;
  const int cls = blockIdx.x >> 6;
  const int blk = blockIdx.x & 63;
  const int tid = threadIdx.x;
  const int lane = tid & 63, wv = tid >> 6;
  const int lr = lane & 15, quad = lane >> 4;

  __shared__ float red[8][32][68];
  __shared__ float pre[32][68];

  const unsigned short* W = (cls == 0) ? Whh0 : (cls == 1) ? Wih1 : Whh1;
  s16x8 bfrag[4][4];
#pragma unroll
  for (int g = 0; g < 4; g++) {
    const unsigned short* wp =
        W + (size_t)(g * 1024 + blk * 16 + lr) * 1024 + wv * 128 + quad * 8;
#pragma unroll
    for (int kb = 0; kb < 4; kb++) bfrag[g][kb] = *(const s16x8*)(wp + kb * 32);
  }

  int* tagL1  = tags;
  int* tagL2b = tags + 64 * TSTRIDE;
  int* tagL2a = tags + 128 * TSTRIDE;
  int* mytag  = tags + (cls * 64 + blk) * TSTRIDE;

  const int batch = tid >> 4, jj = tid & 15;
  float cst = 0.0f;

  const int o = tid * 4;
  const int b2 = o >> 6, col0 = o & 63;
  const int gg_ = col0 >> 4, j0 = col0 & 15;
  const float* ihp0 = ih + (size_t)b2 * T * 4096 + gg_ * 1024 + blk * 16 + j0;

  float4 iv = {0.f, 0.f, 0.f, 0.f};
  if (cls == 0)      iv = *(const float4*)(ihp0);
  else if (cls == 1) iv = *(const float4*)(b1 + gg_ * 1024 + blk * 16 + j0);

  for (int s = 0; s < T; s++) {
    // ---- per-wave polls: each wave waits only on the producers it reads ----
    if (cls == 0) {
      if (lane < 8) spin_tag(tagL1 + (8 * wv + lane) * TSTRIDE, 8 * s);
    } else if (cls == 1) {
      if (lane < 8) spin_tag(tagL1 + (8 * wv + lane) * TSTRIDE, 8 * (s + 1));
      if (lane == 0) spin_tag(tagL2a + blk * TSTRIDE, 8 * (s - 3));  // P-ring
    } else {
      if (lane < 8) spin_tag(tagL2a + (8 * wv + lane) * TSTRIDE, 8 * s);
      if (lane == 0) spin_tag(tagL2b + blk * TSTRIDE, 8 * (s + 1));  // P(s)
    }
    asm volatile("" ::: "memory");  // no hoisting data loads above polls

    // cls2: issue partner-P load NOW so its RT hides under MFMA
    float4 smp = {0.f, 0.f, 0.f, 0.f};
    if (cls == 2)
      smp = load16f_llc(Pring + (size_t)(s & 3) * PSLOT + blk * 2048 + b2 * 64 + col0);

    // source: cls0 h1(s-1); cls1 h1(s); cls2 h2(s-1). slot = step & 3.
    const unsigned short* src =
        (cls == 0) ? h1x + ((s + 3) & 3) * HSLOT
      : (cls == 1) ? h1x + (s & 3) * HSLOT
                   : h2x + ((s + 3) & 3) * HSLOT;

    // hoist all fragment loads (one LLC latency for the whole step)
    u64 r0[4][2], r1[4][2];
#pragma unroll
    for (int kb = 0; kb < 4; kb++) {
      const int d = wv * 128 + kb * 32 + quad * 8;       // global k-dim
      const unsigned short* pp = src + (d >> 4) * 512 + (d & 15);
      const u64* q0 = (const u64*)(pp + lr * 16);
      const u64* q1 = (const u64*)(pp + (16 + lr) * 16);
      r0[kb][0] = ld_llc64(q0); r0[kb][1] = ld_llc64(q0 + 1);
      r1[kb][0] = ld_llc64(q1); r1[kb][1] = ld_llc64(q1 + 1);
    }

    f32x4 acc0[4] = {}, acc1[4] = {};
#pragma unroll
    for (int kb = 0; kb < 4; kb++) {
      union { u64 u[2]; s16x8 v; } A0, A1;
      A0.u[0] = r0[kb][0]; A0.u[1] = r0[kb][1];
      A1.u[0] = r1[kb][0]; A1.u[1] = r1[kb][1];
#pragma unroll
      for (int g = 0; g < 4; g++) {
        acc0[g] = mfma16(A0.v, bfrag[g][kb], acc0[g]);
        acc1[g] = mfma16(A1.v, bfrag[g][kb], acc1[g]);
      }
    }
#pragma unroll
    for (int g = 0; g < 4; g++)
#pragma unroll
      for (int r = 0; r < 4; r++) {
        red[wv][quad * 4 + r][g * 16 + lr] = acc0[g][r];
        red[wv][16 + quad * 4 + r][g * 16 + lr] = acc1[g][r];
      }
    __syncthreads();  // A

    // ---- reduce 8 partials + iv (cls2: iv = partner's P(s), prefetched) ----
    float4 sm = (cls == 2) ? smp : iv;
#pragma unroll
    for (int p = 0; p < 8; p++) {
      float4 r = *(const float4*)&red[p][b2][col0];
      sm.x += r.x; sm.y += r.y; sm.z += r.z; sm.w += r.w;
    }

    if (cls == 0) {
      // h1-slot guard, ring-4: cls1 must have consumed h1(s-4) (lagging)
      if (tid < 64) spin_tag(tagL2b + tid * TSTRIDE, 8 * (s - 3));
      if (s + 1 < T) iv = *(const float4*)(ihp0 + (size_t)(s + 1) * 4096);
    }

    float hv = 0.0f;
    if (cls == 1) {
      // P(s) = pre-activations, straight to the ring (no gates)
      store16f_llc(Pring + (size_t)(s & 3) * PSLOT + blk * 2048 + b2 * 64 + col0, sm);
      __syncthreads();  // B' (FIX1: separates red reads from next red writes)
    } else {
      *(float4*)&pre[b2][col0] = sm;
      __syncthreads();  // B (also orders the tid<64 guard before h stores)
      float pi = pre[batch][jj];
      float pf = pre[batch][16 + jj];
      float pg = pre[batch][32 + jj];
      float po = pre[batch][48 + jj];
      float ig = 1.0f / (1.0f + __expf(-pi));
      float fg = 1.0f / (1.0f + __expf(-pf));
      float g  = 1.0f - 2.0f / (__expf(2.0f * pg) + 1.0f);  // tanh, safe
      float og = 1.0f / (1.0f + __expf(-po));
      cst = fg * cst + ig * g;
      hv = og * (1.0f - 2.0f / (__expf(2.0f * cst) + 1.0f));
      unsigned hb32 = f2bf(hv);
      unsigned other = __shfl_xor(hb32, 1);  // partner (same batch, jj^1)
      unsigned* dst = (unsigned*)((cls == 0 ? h1x : h2x) + (s & 3) * HSLOT);
      if ((tid & 1) == 0)
        __hip_atomic_store(dst + blk * 256 + batch * 8 + (jj >> 1),
                           (hb32 & 0xFFFFu) | (other << 16),
                           __ATOMIC_RELAXED, __HIP_MEMORY_SCOPE_AGENT);
    }
    // per-wave: drain OWN stores, then publish. No block barrier in the tail.
    asm volatile("s_waitcnt vmcnt(0)" ::: "memory");
    if (lane == 0)
      __hip_atomic_fetch_add(mytag, 1, __ATOMIC_RELAXED, __HIP_MEMORY_SCOPE_AGENT);
    if (cls == 2)  // out store after publish: not part of the drain
      out[((size_t)(batch * T + s)) * H + blk * 16 + jj] = hv;
  }
}

// ---------------- launcher ----------------
extern "C" void kernel_launch(void* const* d_in, const int* in_sizes, int n_in,
                              void* d_out, int out_size, void* d_ws, size_t ws_size,
                              hipStream_t stream) {
  const float* x    = (const float*)d_in[0];
  const float* Wih0 = (const float*)d_in[1];
  const float* Whh0 = (const float*)d_in[2];
  const float* b0   = (const float*)d_in[3];
  const float* Wih1 = (const float*)d_in[4];
  const float* Whh1 = (const float*)d_in[5];
  const float* b1   = (const float*)d_in[6];
  float* out = (float*)d_out;

  const size_t NW = 4096ull * 1024;  // weight elems
  const size_t NX = 8192ull * 1024;  // x elems (B*T x H)

  char* ws = (char*)d_ws;
  size_t off = 0;
  auto alloc = [&](size_t bytes) {
    char* p = ws + off;
    off += (bytes + 255) & ~(size_t)255;
    return p;
  };
  unsigned short* wih0b = (unsigned short*)alloc(NW * 2);
  unsigned short* whh0b = (unsigned short*)alloc(NW * 2);
  unsigned short* wih1b = (unsigned short*)alloc(NW * 2);
  unsigned short* whh1b = (unsigned short*)alloc(NW * 2);
  unsigned short* xb    = (unsigned short*)alloc(NX * 2);
  float* ihbuf          = (float*)alloc(8192ull * 4096 * 4);
  unsigned short* h1x   = (unsigned short*)alloc(4ull * HSLOT * 2);
  unsigned short* h2x   = (unsigned short*)alloc(4ull * HSLOT * 2);
  float* Pring          = (float*)alloc(4ull * PSLOT * 4);
  int* tags             = (int*)alloc(3ull * 64 * TSTRIDE * 4);

  hipMemsetAsync(tags, 0, 3ull * 64 * TSTRIDE * 4, stream);
  hipMemsetAsync(h1x, 0, 4ull * HSLOT * 2, stream);
  hipMemsetAsync(h2x, 0, 4ull * HSLOT * 2, stream);

  f2bf_kernel<<<NW / 1024, 256, 0, stream>>>(Wih0, wih0b, (int)NW);
  f2bf_kernel<<<NW / 1024, 256, 0, stream>>>(Whh0, whh0b, (int)NW);
  f2bf_kernel<<<NW / 1024, 256, 0, stream>>>(Wih1, wih1b, (int)NW);
  f2bf_kernel<<<NW / 1024, 256, 0, stream>>>(Whh1, whh1b, (int)NW);
  f2bf_kernel<<<NX / 1024, 256, 0, stream>>>(x, xb, (int)NX);

  // layer-1 input projection (one big GEMM), then the dataflow pipeline
  gemm_bias<<<dim3(64, 32), 256, 0, stream>>>(xb, wih0b, b0, ihbuf, 8192, 4096, 1024);
  lstm_pipe<<<192, 512, 0, stream>>>(ihbuf, whh0b, wih1b, whh1b, b1,
                                     h1x, h2x, Pring, tags, out);
}

// Round 4
// 1286.985 us; speedup vs baseline: 1.6246x; 1.2451x over previous
//
#include <hip/hip_runtime.h>
#include <cstdint>
#include <cstddef>

typedef short s16x8 __attribute__((ext_vector_type(8)));
typedef float f32x4 __attribute__((ext_vector_type(4)));
typedef unsigned long long u64;

__device__ __forceinline__ f32x4 mfma16(s16x8 a, s16x8 b, f32x4 c) {
  return __builtin_amdgcn_mfma_f32_16x16x32_bf16(a, b, c, 0, 0, 0);
}

__device__ __forceinline__ unsigned short f2bf(float f) {
  unsigned u = __float_as_uint(f);
  u = (u + 0x7FFFu + ((u >> 16) & 1u)) >> 16;
  return (unsigned short)u;
}

// LLC-coherent ops (bypass L1/L2, hit the coherence point directly).
__device__ __forceinline__ u64 ld_llc64(const u64* q) {
  return __hip_atomic_load(q, __ATOMIC_RELAXED, __HIP_MEMORY_SCOPE_AGENT);
}
__device__ __forceinline__ float4 load16f_llc(const float* p) {
  union { u64 u[2]; float4 v; } r;
  const u64* q = (const u64*)p;
  r.u[0] = __hip_atomic_load(q,     __ATOMIC_RELAXED, __HIP_MEMORY_SCOPE_AGENT);
  r.u[1] = __hip_atomic_load(q + 1, __ATOMIC_RELAXED, __HIP_MEMORY_SCOPE_AGENT);
  return r.v;
}
__device__ __forceinline__ void store16f_llc(float* p, float4 v) {
  union { float4 v; u64 u[2]; } r; r.v = v;
  u64* q = (u64*)p;
  __hip_atomic_store(q,     r.u[0], __ATOMIC_RELAXED, __HIP_MEMORY_SCOPE_AGENT);
  __hip_atomic_store(q + 1, r.u[1], __ATOMIC_RELAXED, __HIP_MEMORY_SCOPE_AGENT);
}

// Depth-3 pipelined spin with sleep: ~3 loads in flight -> sampling interval
// ~RT/3; sleep keeps idle-poll pressure off the LLC. Monotonic >= check.
__device__ __forceinline__ void spin_tag(const int* t, int target) {
  if (target <= 0) return;
  int a = __hip_atomic_load(t, __ATOMIC_RELAXED, __HIP_MEMORY_SCOPE_AGENT);
  if (a >= target) return;
  int b = __hip_atomic_load(t, __ATOMIC_RELAXED, __HIP_MEMORY_SCOPE_AGENT);
  int c = __hip_atomic_load(t, __ATOMIC_RELAXED, __HIP_MEMORY_SCOPE_AGENT);
  while (a < target) {
    a = b; b = c;
    __builtin_amdgcn_s_sleep(1);
    c = __hip_atomic_load(t, __ATOMIC_RELAXED, __HIP_MEMORY_SCOPE_AGENT);
  }
}

// ---------------- fp32 -> bf16 conversion ----------------
__global__ void f2bf_kernel(const float* __restrict__ src,
                            unsigned short* __restrict__ dst, int n) {
  int i = (blockIdx.x * blockDim.x + threadIdx.x) * 4;
  if (i >= n) return;
  float4 v = *(const float4*)(src + i);
  ushort4 o;
  o.x = f2bf(v.x); o.y = f2bf(v.y); o.z = f2bf(v.z); o.w = f2bf(v.w);
  *(ushort4*)(dst + i) = o;
}

// ---------------- GEMM: C[M,N] = A[M,K] * W[N,K]^T + bias ----------------
__global__ __launch_bounds__(256) void gemm_bias(
    const unsigned short* __restrict__ A,
    const unsigned short* __restrict__ W,
    const float* __restrict__ bias,
    float* __restrict__ C,
    int M, int N, int K)
{
  __shared__ unsigned short As[128 * 40];
  __shared__ unsigned short Bs[128 * 40];
  const int bm = blockIdx.x, bn = blockIdx.y;
  const int tid = threadIdx.x;
  const int lane = tid & 63, wave = tid >> 6;
  const int wm = wave & 1, wn = wave >> 1;
  const int lr = lane & 15, quad = lane >> 4;
  f32x4 acc[4][4] = {};
  const size_t abase = (size_t)bm * 128 * K;
  const size_t bbase = (size_t)bn * 128 * K;
  for (int k0 = 0; k0 < K; k0 += 32) {
#pragma unroll
    for (int u0 = 0; u0 < 2; u0++) {
      int u = tid + u0 * 256;
      int row = u >> 2, seg = u & 3;
      *(uint4*)(As + row * 40 + seg * 8) =
          *(const uint4*)(A + abase + (size_t)row * K + k0 + seg * 8);
      *(uint4*)(Bs + row * 40 + seg * 8) =
          *(const uint4*)(W + bbase + (size_t)row * K + k0 + seg * 8);
    }
    __syncthreads();
    s16x8 af[4], bf[4];
#pragma unroll
    for (int i = 0; i < 4; i++)
      af[i] = *(const s16x8*)(As + (wm * 64 + i * 16 + lr) * 40 + quad * 8);
#pragma unroll
    for (int j = 0; j < 4; j++)
      bf[j] = *(const s16x8*)(Bs + (wn * 64 + j * 16 + lr) * 40 + quad * 8);
#pragma unroll
    for (int i = 0; i < 4; i++)
#pragma unroll
      for (int j = 0; j < 4; j++)
        acc[i][j] = mfma16(af[i], bf[j], acc[i][j]);
    __syncthreads();
  }
#pragma unroll
  for (int i = 0; i < 4; i++)
#pragma unroll
    for (int j = 0; j < 4; j++) {
      int col = bn * 128 + wn * 64 + j * 16 + lr;
      float bv = bias ? bias[col] : 0.0f;
#pragma unroll
      for (int r = 0; r < 4; r++) {
        int row = bm * 128 + wm * 64 + i * 16 + quad * 4 + r;
        C[(size_t)row * N + col] = acc[i][j][r] + bv;
      }
    }
}

// ---------------- dataflow 3-stage pipelined LSTM ----------------
// R10 = R6 publish discipline (vmcnt(0)+syncC+single tid0 tag store; R9's
// per-wave fetch_add regressed: 8 serialized RMWs on a line polled by ~128
// consumers) + three latency cuts:
//   1. cls2's partner-P load prefetched right after polls (R6 had it exposed
//      after syncA -> cls2 carried +1 RT and set the global period).
//   2. Single fully-parallel poll: per-lane (ptr, delta) covers data tags
//      (lanes 0-7) AND the anti-trample guards (lanes 8-15 / lane 8) in one
//      exec-masked spin. cls0's 64-line h1-slot guard moves to the TOP,
//      distributed 8/wave; syncA orders all guards before any h store.
//   3. syncB dropped: the pre[] gate exchange is wave-internal (writer lanes
//      of row b2 == reader lanes of batch b2, same 16 threads), so the
//      compiler's own lgkmcnt suffices. Barriers/step: 3 -> 2 (syncA, syncC).
// Kept from R9: ring-4 h slots, hoisted fragment loads, depth-3+sleep spin.
// Classes (64 blocks each, 16 output dims per block, weights in VGPRs):
//   cls0 L1 : h1(s) = gate(ih(s) + Whh0 h1(s-1))   tagL1
//   cls1 L2b: P(s)  = Wih1 h1(s) + b1  -> 4-ring   tagL2b (point-to-point)
//   cls2 L2a: h2(s) = gate(P(s) + Whh1 h2(s-1))    tagL2a; writes out
// Tag = completed steps (tid0 store after block drain). Anti-trample, ring-4:
//   cls0 h1(s) over h1(s-4): peers tagL1>=s (top, collective), cls1 tagL2b>=
//   s-3 (top lanes 8-15, 8/wave, collective; syncA < stores). cls1 P(s) over
//   P(s-4): partner tagL2a>=s-3 (lane 8). cls2 h2(s) over h2(s-4): peers
//   tagL2a>=s (top). All overwrites ordered after every prior consumption.
// Deadlock-free: cls0@s <- cls1@s-3 <- cls0@s-2, cls2@s-6 <- ... all lagging.
#define TSTRIDE 32          // ints per tag (128B line)
#define HSLOT  32768        // shorts per h slot: 64 blk * 32 batch * 16 dim
#define PSLOT  (64 * 2048)  // floats per P slot: 64 blk * 32 batch * 64 col

__global__ __launch_bounds__(512, 2) void lstm_pipe(
    const float* __restrict__ ih,             // [(b*T+t)*4096 + g*1024 + d]
    const unsigned short* __restrict__ Whh0,  // [4096,1024] bf16
    const unsigned short* __restrict__ Wih1,  // [4096,1024] bf16
    const unsigned short* __restrict__ Whh1,  // [4096,1024] bf16
    const float* __restrict__ b1,             // [4096] fp32
    unsigned short* __restrict__ h1x,         // [4][64][32][16] bf16 (zeroed)
    unsigned short* __restrict__ h2x,         // [4][64][32][16] bf16 (zeroed)
    float* __restrict__ Pring,                // [4][64][32][64] fp32
    int* __restrict__ tags,                   // [3][64][TSTRIDE] (zeroed)
    float* __restrict__ out)                  // [32][256][1024] fp32
{
  const int T = 256, H = 1024;
  const int cls = blockIdx.x >> 6;
  const int blk = blockIdx.x & 63;
  const int tid = threadIdx.x;
  const int lane = tid & 63, wv = tid >> 6;
  const int lr = lane & 15, quad = lane >> 4;

  __shared__ float red[8][32][68];
  __shared__ float pre[32][68];

  const unsigned short* W = (cls == 0) ? Whh0 : (cls == 1) ? Wih1 : Whh1;
  s16x8 bfrag[4][4];
#pragma unroll
  for (int g = 0; g < 4; g++) {
    const unsigned short* wp =
        W + (size_t)(g * 1024 + blk * 16 + lr) * 1024 + wv * 128 + quad * 8;
#pragma unroll
    for (int kb = 0; kb < 4; kb++) bfrag[g][kb] = *(const s16x8*)(wp + kb * 32);
  }

  int* tagL1  = tags;
  int* tagL2b = tags + 64 * TSTRIDE;
  int* tagL2a = tags + 128 * TSTRIDE;
  int* mytag  = tags + (cls * 64 + blk) * TSTRIDE;

  // ---- per-lane poll assignment: one parallel spin covers everything ----
  const int* pollPtr = nullptr;
  int pollDelta = 0;
  if (cls == 0) {
    if (lane < 8)       { pollPtr = tagL1  + (8 * wv + lane) * TSTRIDE;     pollDelta = 0;  }
    else if (lane < 16) { pollPtr = tagL2b + (8 * wv + lane - 8) * TSTRIDE; pollDelta = -3; }
  } else if (cls == 1) {
    if (lane < 8)       { pollPtr = tagL1  + (8 * wv + lane) * TSTRIDE;     pollDelta = 1;  }
    else if (lane == 8) { pollPtr = tagL2a + blk * TSTRIDE;                 pollDelta = -3; }
  } else {
    if (lane < 8)       { pollPtr = tagL2a + (8 * wv + lane) * TSTRIDE;     pollDelta = 0;  }
    else if (lane == 8) { pollPtr = tagL2b + blk * TSTRIDE;                 pollDelta = 1;  }
  }

  const int batch = tid >> 4, jj = tid & 15;
  float cst = 0.0f;

  const int o = tid * 4;
  const int b2 = o >> 6, col0 = o & 63;
  const int gg_ = col0 >> 4, j0 = col0 & 15;
  const float* ihp0 = ih + (size_t)b2 * T * 4096 + gg_ * 1024 + blk * 16 + j0;

  float4 iv = {0.f, 0.f, 0.f, 0.f};
  if (cls == 0)      iv = *(const float4*)(ihp0);
  else if (cls == 1) iv = *(const float4*)(b1 + gg_ * 1024 + blk * 16 + j0);

  for (int s = 0; s < T; s++) {
    // ---- single parallel poll: data tags + anti-trample guards ----
    if (pollPtr) spin_tag(pollPtr, s + pollDelta);
    asm volatile("" ::: "memory");  // no hoisting data loads above polls

    // cls2: issue partner-P load NOW so its RT hides under MFMA
    float4 smp = {0.f, 0.f, 0.f, 0.f};
    if (cls == 2)
      smp = load16f_llc(Pring + (size_t)(s & 3) * PSLOT + blk * 2048 + b2 * 64 + col0);

    // source: cls0 h1(s-1); cls1 h1(s); cls2 h2(s-1). slot = step & 3.
    const unsigned short* src =
        (cls == 0) ? h1x + ((s + 3) & 3) * HSLOT
      : (cls == 1) ? h1x + (s & 3) * HSLOT
                   : h2x + ((s + 3) & 3) * HSLOT;

    // hoist all fragment loads (one LLC latency for the whole step)
    u64 r0[4][2], r1[4][2];
#pragma unroll
    for (int kb = 0; kb < 4; kb++) {
      const int d = wv * 128 + kb * 32 + quad * 8;       // global k-dim
      const unsigned short* pp = src + (d >> 4) * 512 + (d & 15);
      const u64* q0 = (const u64*)(pp + lr * 16);
      const u64* q1 = (const u64*)(pp + (16 + lr) * 16);
      r0[kb][0] = ld_llc64(q0); r0[kb][1] = ld_llc64(q0 + 1);
      r1[kb][0] = ld_llc64(q1); r1[kb][1] = ld_llc64(q1 + 1);
    }

    f32x4 acc0[4] = {}, acc1[4] = {};
#pragma unroll
    for (int kb = 0; kb < 4; kb++) {
      union { u64 u[2]; s16x8 v; } A0, A1;
      A0.u[0] = r0[kb][0]; A0.u[1] = r0[kb][1];
      A1.u[0] = r1[kb][0]; A1.u[1] = r1[kb][1];
#pragma unroll
      for (int g = 0; g < 4; g++) {
        acc0[g] = mfma16(A0.v, bfrag[g][kb], acc0[g]);
        acc1[g] = mfma16(A1.v, bfrag[g][kb], acc1[g]);
      }
    }
#pragma unroll
    for (int g = 0; g < 4; g++)
#pragma unroll
      for (int r = 0; r < 4; r++) {
        red[wv][quad * 4 + r][g * 16 + lr] = acc0[g][r];
        red[wv][16 + quad * 4 + r][g * 16 + lr] = acc1[g][r];
      }
    __syncthreads();  // A (orders: guards < h-stores; red writes < reads)

    // ---- reduce 8 partials + iv (cls2: iv = partner's P(s), prefetched) ----
    float4 sm = (cls == 2) ? smp : iv;
#pragma unroll
    for (int p = 0; p < 8; p++) {
      float4 r = *(const float4*)&red[p][b2][col0];
      sm.x += r.x; sm.y += r.y; sm.z += r.z; sm.w += r.w;
    }

    if (cls == 0 && s + 1 < T)
      iv = *(const float4*)(ihp0 + (size_t)(s + 1) * 4096);

    float hv = 0.0f;
    if (cls == 1) {
      // P(s) = pre-activations, straight to the ring (no gates)
      store16f_llc(Pring + (size_t)(s & 3) * PSLOT + blk * 2048 + b2 * 64 + col0, sm);
    } else {
      // gate exchange is WAVE-INTERNAL: writer lanes of row b2 == reader
      // lanes of batch==b2 (same 16 threads). Compiler-inserted lgkmcnt
      // orders the may-aliasing LDS write->read; no barrier needed.
      *(float4*)&pre[b2][col0] = sm;
      float pi = pre[batch][jj];
      float pf = pre[batch][16 + jj];
      float pg = pre[batch][32 + jj];
      float po = pre[batch][48 + jj];
      float ig = 1.0f / (1.0f + __expf(-pi));
      float fg = 1.0f / (1.0f + __expf(-pf));
      float g  = 1.0f - 2.0f / (__expf(2.0f * pg) + 1.0f);  // tanh, safe
      float og = 1.0f / (1.0f + __expf(-po));
      cst = fg * cst + ig * g;
      hv = og * (1.0f - 2.0f / (__expf(2.0f * cst) + 1.0f));
      unsigned hb32 = f2bf(hv);
      unsigned other = __shfl_xor(hb32, 1);  // partner (same batch, jj^1)
      unsigned* dst = (unsigned*)((cls == 0 ? h1x : h2x) + (s & 3) * HSLOT);
      if ((tid & 1) == 0)
        __hip_atomic_store(dst + blk * 256 + batch * 8 + (jj >> 1),
                           (hb32 & 0xFFFFu) | (other << 16),
                           __ATOMIC_RELAXED, __HIP_MEMORY_SCOPE_AGENT);
    }
    // drain all waves' stores, rendezvous, single publish (R6 discipline)
    asm volatile("s_waitcnt vmcnt(0)" ::: "memory");
    __syncthreads();  // C (also separates red reads from next red writes)
    if (tid == 0)
      __hip_atomic_store(mytag, s + 1, __ATOMIC_RELAXED, __HIP_MEMORY_SCOPE_AGENT);
    if (cls == 2)  // out store after publish: not on the forward path
      out[((size_t)(batch * T + s)) * H + blk * 16 + jj] = hv;
  }
}

// ---------------- launcher ----------------
extern "C" void kernel_launch(void* const* d_in, const int* in_sizes, int n_in,
                              void* d_out, int out_size, void* d_ws, size_t ws_size,
                              hipStream_t stream) {
  const float* x    = (const float*)d_in[0];
  const float* Wih0 = (const float*)d_in[1];
  const float* Whh0 = (const float*)d_in[2];
  const float* b0   = (const float*)d_in[3];
  const float* Wih1 = (const float*)d_in[4];
  const float* Whh1 = (const float*)d_in[5];
  const float* b1   = (const float*)d_in[6];
  float* out = (float*)d_out;

  const size_t NW = 4096ull * 1024;  // weight elems
  const size_t NX = 8192ull * 1024;  // x elems (B*T x H)

  char* ws = (char*)d_ws;
  size_t off = 0;
  auto alloc = [&](size_t bytes) {
    char* p = ws + off;
    off += (bytes + 255) & ~(size_t)255;
    return p;
  };
  unsigned short* wih0b = (unsigned short*)alloc(NW * 2);
  unsigned short* whh0b = (unsigned short*)alloc(NW * 2);
  unsigned short* wih1b = (unsigned short*)alloc(NW * 2);
  unsigned short* whh1b = (unsigned short*)alloc(NW * 2);
  unsigned short* xb    = (unsigned short*)alloc(NX * 2);
  float* ihbuf          = (float*)alloc(8192ull * 4096 * 4);
  unsigned short* h1x   = (unsigned short*)alloc(4ull * HSLOT * 2);
  unsigned short* h2x   = (unsigned short*)alloc(4ull * HSLOT * 2);
  float* Pring          = (float*)alloc(4ull * PSLOT * 4);
  int* tags             = (int*)alloc(3ull * 64 * TSTRIDE * 4);

  hipMemsetAsync(tags, 0, 3ull * 64 * TSTRIDE * 4, stream);
  hipMemsetAsync(h1x, 0, 4ull * HSLOT * 2, stream);
  hipMemsetAsync(h2x, 0, 4ull * HSLOT * 2, stream);

  f2bf_kernel<<<NW / 1024, 256, 0, stream>>>(Wih0, wih0b, (int)NW);
  f2bf_kernel<<<NW / 1024, 256, 0, stream>>>(Whh0, whh0b, (int)NW);
  f2bf_kernel<<<NW / 1024, 256, 0, stream>>>(Wih1, wih1b, (int)NW);
  f2bf_kernel<<<NW / 1024, 256, 0, stream>>>(Whh1, whh1b, (int)NW);
  f2bf_kernel<<<NX / 1024, 256, 0, stream>>>(x, xb, (int)NX);

  // layer-1 input projection (one big GEMM), then the dataflow pipeline
  gemm_bias<<<dim3(64, 32), 256, 0, stream>>>(xb, wih0b, b0, ihbuf, 8192, 4096, 1024);
  lstm_pipe<<<192, 512, 0, stream>>>(ihbuf, whh0b, wih1b, whh1b, b1,
                                     h1x, h2x, Pring, tags, out);
}